// Round 7
// baseline (763.601 us; speedup 1.0000x reference)
//
#include <hip/hip_runtime.h>
#include <cstdint>

#define NN 50000
#define EE 800000
#define DIN 128
#define DD 256
#define DOUT 64
#define NLAYERS 3
#define LN_EPS 1e-5f
#define NB_SCAN ((NN + 255) / 256)

typedef __attribute__((ext_vector_type(8))) _Float16 h8;  // fp16 MFMA fragment (4 VGPR)
typedef __attribute__((ext_vector_type(4))) _Float16 h4;
typedef __attribute__((ext_vector_type(4))) float f4;     // MFMA accumulator

__device__ __forceinline__ float waveSum(float v) {
#pragma unroll
  for (int m = 1; m < 64; m <<= 1) v += __shfl_xor(v, m, 64);
  return v;
}

// fp16 2-limb split: a = h1 + h2 + O(2^-22 |a|); each limb product is exact in
// fp32 (11x11-bit mantissas), so 3-term MFMA reconstruction is fp32-grade.
__device__ __forceinline__ void splith(const float4& a, const float4& b, h8& p1, h8& p2) {
  float t[8] = {a.x, a.y, a.z, a.w, b.x, b.y, b.z, b.w};
#pragma unroll
  for (int i = 0; i < 8; ++i) {
    _Float16 x = (_Float16)t[i];
    p1[i] = x;
    p2[i] = (_Float16)(t[i] - (float)x);
  }
}

__device__ __forceinline__ void split4(const float4& a, h4& q1, h4& q2) {
  float t[4] = {a.x, a.y, a.z, a.w};
#pragma unroll
  for (int i = 0; i < 4; ++i) {
    _Float16 x = (_Float16)t[i];
    q1[i] = x;
    q2[i] = (_Float16)(t[i] - (float)x);
  }
}

// hn (fp16 limbs) = LN(h); SR/SA gate-net scalars. One wave per node.
__global__ __launch_bounds__(256) void k_ln_scalars(
    const float* __restrict__ h, const float* __restrict__ ln_g, const float* __restrict__ ln_b,
    const float* __restrict__ Wir, const float* __restrict__ Wia,
    const float* __restrict__ Wor, const float* __restrict__ Woa,
    _Float16* __restrict__ hn1, _Float16* __restrict__ hn2,
    float* __restrict__ SR, float* __restrict__ SA) {
  const int lane = threadIdx.x & 63;
  const int node = blockIdx.x * 4 + (threadIdx.x >> 6);
  if (node >= NN) return;
  const float4 hv = *(const float4*)(h + (size_t)node * DD + lane * 4);
  float m = waveSum(hv.x + hv.y + hv.z + hv.w) * (1.f / DD);
  float dx = hv.x - m, dy = hv.y - m, dz = hv.z - m, dw = hv.w - m;
  float var = waveSum(dx * dx + dy * dy + dz * dz + dw * dw) * (1.f / DD);
  float rs = 1.f / sqrtf(var + LN_EPS);
  const float4 g = *(const float4*)(ln_g + lane * 4);
  const float4 bb = *(const float4*)(ln_b + lane * 4);
  float4 o;
  o.x = fmaf(dx * rs, g.x, bb.x);
  o.y = fmaf(dy * rs, g.y, bb.y);
  o.z = fmaf(dz * rs, g.z, bb.z);
  o.w = fmaf(dw * rs, g.w, bb.w);
  {
    h4 q1, q2;
    split4(o, q1, q2);
    *(h4*)(hn1 + (size_t)node * DD + lane * 4) = q1;
    *(h4*)(hn2 + (size_t)node * DD + lane * 4) = q2;
  }
  float p[8];
  const float4 a0 = *(const float4*)(Wir + 8 * lane);
  const float4 a1 = *(const float4*)(Wir + 8 * lane + 4);
  p[0] = o.x * a0.x + o.y * a0.z + o.z * a1.x + o.w * a1.z;
  p[1] = o.x * a0.y + o.y * a0.w + o.z * a1.y + o.w * a1.w;
  const float4 c0 = *(const float4*)(Wia + 8 * lane);
  const float4 c1 = *(const float4*)(Wia + 8 * lane + 4);
  p[2] = o.x * c0.x + o.y * c0.z + o.z * c1.x + o.w * c1.z;
  p[3] = o.x * c0.y + o.y * c0.w + o.z * c1.y + o.w * c1.w;
  const float4 e0 = *(const float4*)(Wor + 8 * lane);
  const float4 e1 = *(const float4*)(Wor + 8 * lane + 4);
  p[4] = o.x * e0.x + o.y * e0.z + o.z * e1.x + o.w * e1.z;
  p[5] = o.x * e0.y + o.y * e0.w + o.z * e1.y + o.w * e1.w;
  const float4 f0 = *(const float4*)(Woa + 8 * lane);
  const float4 f1 = *(const float4*)(Woa + 8 * lane + 4);
  p[6] = o.x * f0.x + o.y * f0.z + o.z * f1.x + o.w * f1.z;
  p[7] = o.x * f0.y + o.y * f0.w + o.z * f1.y + o.w * f1.w;
#pragma unroll
  for (int j = 0; j < 8; ++j) p[j] = waveSum(p[j]);
  if (lane == 0) {
    *(float4*)(SR + (size_t)node * 4) = make_float4(p[0], p[1], p[4], p[5]);
    *(float4*)(SA + (size_t)node * 4) = make_float4(p[2], p[3], p[6], p[7]);
  }
}

// ---- CSR build (edge_index constant per call; rebuilt every launch) ----
__global__ void k_zero_deg(int* __restrict__ deg) {
  int i = blockIdx.x * 256 + threadIdx.x;
  if (i < NN) deg[i] = 0;
}

__global__ void k_deg(const int* __restrict__ ei, int* __restrict__ deg) {
  int e = blockIdx.x * 256 + threadIdx.x;
  if (e < EE) atomicAdd(&deg[ei[e]], 1);
}

__global__ __launch_bounds__(256) void k_scan1(const int* __restrict__ deg,
                                               int* __restrict__ bsum) {
  __shared__ int sm[256];
  const int t = threadIdx.x;
  int i = blockIdx.x * 256 + t;
  sm[t] = (i < NN) ? deg[i] : 0;
  __syncthreads();
  for (int off = 128; off > 0; off >>= 1) {
    if (t < off) sm[t] += sm[t + off];
    __syncthreads();
  }
  if (t == 0) bsum[blockIdx.x] = sm[0];
}

__global__ __launch_bounds__(256) void k_scan2(const int* __restrict__ bsum,
                                               int* __restrict__ boff,
                                               int* __restrict__ rowptr) {
  __shared__ int sm[256];
  const int t = threadIdx.x;
  int v = (t < NB_SCAN) ? bsum[t] : 0;
  sm[t] = v;
  __syncthreads();
  for (int off = 1; off < 256; off <<= 1) {
    int x = (t >= off) ? sm[t - off] : 0;
    __syncthreads();
    sm[t] += x;
    __syncthreads();
  }
  if (t < NB_SCAN) boff[t] = sm[t] - v;  // exclusive prefix
  if (t == 0) rowptr[NN] = sm[255];      // total edge count
}

__global__ __launch_bounds__(256) void k_scan3(const int* __restrict__ deg,
                                               const int* __restrict__ boff,
                                               int* __restrict__ rowptr,
                                               int* __restrict__ cursor) {
  __shared__ int sm[256];
  const int t = threadIdx.x;
  int i = blockIdx.x * 256 + t;
  int v = (i < NN) ? deg[i] : 0;
  sm[t] = v;
  __syncthreads();
  for (int off = 1; off < 256; off <<= 1) {
    int x = (t >= off) ? sm[t - off] : 0;
    __syncthreads();
    sm[t] += x;
    __syncthreads();
  }
  if (i < NN) {
    int r = boff[blockIdx.x] + sm[t] - v;
    rowptr[i] = r;
    cursor[i] = r;
  }
}

__global__ void k_fill(const int* __restrict__ ei, int* __restrict__ cursor,
                       int* __restrict__ csr_v) {
  int e = blockIdx.x * 256 + threadIdx.x;
  if (e >= EE) return;
  int u = ei[e], v = ei[EE + e];
  int slot = atomicAdd(&cursor[u], 1);
  csr_v[slot] = v;
}

// conv weight prep, all layers: [W_root;W_agg] -> [l][n][k] fp16 limbs, K=512
__global__ void k_prep_conv(const float* __restrict__ Wr, const float* __restrict__ Wa,
                            _Float16* __restrict__ W1, _Float16* __restrict__ W2) {
  int idx = blockIdx.x * 256 + threadIdx.x;
  if (idx >= NLAYERS * DD * 2 * DD) return;
  int l = idx >> 17;           // 256*512 = 2^17
  int rem = idx & 131071;
  int n = rem >> 9, k = rem & 511;
  float w = (k < DD) ? Wr[((size_t)l * DD + k) * DD + n]
                     : Wa[((size_t)l * DD + (k - DD)) * DD + n];
  _Float16 x = (_Float16)w;
  W1[idx] = x;
  W2[idx] = (_Float16)(w - (float)x);
}

// enc + dec weight prep in one kernel: -> [n][k] fp16 limbs
__global__ void k_prep_ed(const float* __restrict__ We, const float* __restrict__ Wd,
                          _Float16* __restrict__ E1, _Float16* __restrict__ E2,
                          _Float16* __restrict__ D1, _Float16* __restrict__ D2) {
  int idx = blockIdx.x * 256 + threadIdx.x;
  if (idx < DIN * DD) {
    int n = idx / DIN, k = idx - n * DIN;
    float w = We[(size_t)k * DD + n];
    _Float16 x = (_Float16)w;
    E1[idx] = x;
    E2[idx] = (_Float16)(w - (float)x);
  } else if (idx < DIN * DD + DD * DOUT) {
    int j = idx - DIN * DD;
    int n = j / DD, k = j - n * DD;
    float w = Wd[(size_t)k * DOUT + n];
    _Float16 x = (_Float16)w;
    D1[j] = x;
    D2[j] = (_Float16)(w - (float)x);
  }
}

// gates: thread per node; gather SA over in-neighbors, add root+bias+gumbel, argmax
__global__ __launch_bounds__(256) void k_gates_csr(
    const int* __restrict__ rowptr, const int* __restrict__ csr_v,
    const float* __restrict__ SR, const float* __restrict__ SA,
    const float* __restrict__ gn, const float* __restrict__ b_in,
    const float* __restrict__ b_out, unsigned char* __restrict__ gin,
    unsigned char* __restrict__ gout, int l) {
  int u = blockIdx.x * 256 + threadIdx.x;
  if (u >= NN) return;
  int beg = rowptr[u], end = rowptr[u + 1];
  float4 a = make_float4(0.f, 0.f, 0.f, 0.f);
  for (int j = beg; j < end; ++j) {
    int v = csr_v[j];
    float4 s = *(const float4*)(SA + (size_t)v * 4);
    a.x += s.x; a.y += s.y; a.z += s.z; a.w += s.w;
  }
  float4 r = *(const float4*)(SR + (size_t)u * 4);
  const float* gi = gn + ((size_t)(l * 2 + 0) * NN + u) * 2;
  const float* go = gn + ((size_t)(l * 2 + 1) * NN + u) * 2;
  float li0 = r.x + a.x + b_in[0] + gi[0];
  float li1 = r.y + a.y + b_in[1] + gi[1];
  gin[u] = (li0 >= li1) ? 1 : 0;  // argmax==0 wins ties, matches jnp.argmax
  float lo0 = r.z + a.z + b_out[0] + go[0];
  float lo1 = r.w + a.w + b_out[1] + go[1];
  gout[u] = (lo0 >= lo1) ? 1 : 0;
}

// agg (fp16 limbs) = gin[u] * sum_{v in N(u)} gout[v]*hn[v]; one wave per node.
__global__ __launch_bounds__(256) void k_wagg_csr(
    const int* __restrict__ rowptr, const int* __restrict__ csr_v,
    const unsigned char* __restrict__ gin, const unsigned char* __restrict__ gout,
    const _Float16* __restrict__ hn1, const _Float16* __restrict__ hn2,
    _Float16* __restrict__ agg1, _Float16* __restrict__ agg2) {
  const int lane = threadIdx.x & 63;
  const int u = blockIdx.x * 4 + (threadIdx.x >> 6);
  if (u >= NN) return;
  float4 acc = make_float4(0.f, 0.f, 0.f, 0.f);
  float4 acc2 = make_float4(0.f, 0.f, 0.f, 0.f);
  if (gin[u]) {
    int beg = rowptr[u], end = rowptr[u + 1];
    for (int j0 = beg; j0 < end; j0 += 64) {
      int rem = end - j0;
      int v = -1;
      if (lane < rem) v = csr_v[j0 + lane];
      int ok = (v >= 0) ? (int)gout[v] : 0;
      unsigned long long mask = __ballot(ok);
      while (mask) {
        int l0 = __builtin_ctzll(mask);
        mask &= mask - 1;
        int vv0 = __shfl(v, l0);
        const h4* p0a = (const h4*)(hn1 + (size_t)vv0 * DD + lane * 4);
        const h4* p0b = (const h4*)(hn2 + (size_t)vv0 * DD + lane * 4);
        if (mask) {
          int l1 = __builtin_ctzll(mask);
          mask &= mask - 1;
          int vv1 = __shfl(v, l1);
          const h4* p1a = (const h4*)(hn1 + (size_t)vv1 * DD + lane * 4);
          const h4* p1b = (const h4*)(hn2 + (size_t)vv1 * DD + lane * 4);
          h4 a0 = *p0a, b0 = *p0b, a1 = *p1a, b1 = *p1b;
          acc.x += (float)a0[0] + (float)b0[0]; acc.y += (float)a0[1] + (float)b0[1];
          acc.z += (float)a0[2] + (float)b0[2]; acc.w += (float)a0[3] + (float)b0[3];
          acc2.x += (float)a1[0] + (float)b1[0]; acc2.y += (float)a1[1] + (float)b1[1];
          acc2.z += (float)a1[2] + (float)b1[2]; acc2.w += (float)a1[3] + (float)b1[3];
        } else {
          h4 a0 = *p0a, b0 = *p0b;
          acc.x += (float)a0[0] + (float)b0[0]; acc.y += (float)a0[1] + (float)b0[1];
          acc.z += (float)a0[2] + (float)b0[2]; acc.w += (float)a0[3] + (float)b0[3];
        }
      }
    }
    acc.x += acc2.x; acc.y += acc2.y; acc.z += acc2.z; acc.w += acc2.w;
  }
  h4 q1, q2;
  split4(acc, q1, q2);
  *(h4*)(agg1 + (size_t)u * DD + lane * 4) = q1;
  *(h4*)(agg2 + (size_t)u * DD + lane * 4) = q2;
}

// Generic fp16-2-limb 3-term MFMA GEMM: outp = [relu](A @ B^T + bias)
// BM=64 rows/block, BN = NFN*32 cols. A either fp32 (split in staging) or
// pre-limbed fp16 planes. 2x2 waves, wave tile 32 x NFN*16.
#define BM 64
#define LDP 40  // halves; 80B row stride (2-way bank aliasing = free, m136)

template <int KTOT, int ASTR, int NFN, int OSTR, bool RELU, bool FP16A, bool DUAL>
__global__ __launch_bounds__(256, 4) void k_mfma_gemm(
    const float* __restrict__ Af,
    const _Float16* __restrict__ A1a, const _Float16* __restrict__ A2a,
    const _Float16* __restrict__ A1b, const _Float16* __restrict__ A2b,
    const _Float16* __restrict__ B1, const _Float16* __restrict__ B2,
    const float* __restrict__ bias, float* __restrict__ outp) {
  constexpr int BN = NFN * 32;
  constexpr int KSTEPS = KTOT / 32;
  __shared__ _Float16 lA1[BM * LDP], lA2[BM * LDP];
  __shared__ _Float16 lB1[BN * LDP], lB2[BN * LDP];
  const int tid = threadIdx.x;
  const int j0 = blockIdx.x * BN;
  const int i0 = blockIdx.y * BM;
  const int lane = tid & 63, w = tid >> 6;
  const int wr = w >> 1, wc = w & 1;
  const int fr = lane & 15, fs = (lane >> 4) * 8;
  const int asr = tid >> 2, asc = (tid & 3) * 8;  // A staging: 8 cols/thread
  int ga = i0 + asr;
  if (ga >= NN) ga = NN - 1;
  const int bsr = (BN == 128) ? (tid >> 1) : (tid >> 2);
  const int bsc = (BN == 128) ? ((tid & 1) * 16) : ((tid & 3) * 8);
  const size_t boff = (size_t)(j0 + bsr) * KTOT + bsc;

  f4 acc[2][NFN];
#pragma unroll
  for (int i = 0; i < 2; ++i)
#pragma unroll
    for (int j = 0; j < NFN; ++j) acc[i][j] = (f4){0.f, 0.f, 0.f, 0.f};

  float4 fa0, fa1;
  h8 ra1, ra2;
  h8 rb1a, rb1b, rb2a, rb2b;
  {  // prefetch K-tile 0
    if constexpr (FP16A) {
      ra1 = *(const h8*)(A1a + (size_t)ga * ASTR + asc);
      ra2 = *(const h8*)(A2a + (size_t)ga * ASTR + asc);
    } else {
      const float* pa = Af + (size_t)ga * ASTR + asc;
      fa0 = *(const float4*)(pa);
      fa1 = *(const float4*)(pa + 4);
    }
    rb1a = *(const h8*)(B1 + boff);
    rb2a = *(const h8*)(B2 + boff);
    if constexpr (BN == 128) {
      rb1b = *(const h8*)(B1 + boff + 8);
      rb2b = *(const h8*)(B2 + boff + 8);
    }
  }
  for (int kt = 0; kt < KSTEPS; ++kt) {
    __syncthreads();
    {
      int o = asr * LDP + asc;
      if constexpr (FP16A) {
        *(h8*)&lA1[o] = ra1;
        *(h8*)&lA2[o] = ra2;
      } else {
        h8 p1, p2;
        splith(fa0, fa1, p1, p2);
        *(h8*)&lA1[o] = p1;
        *(h8*)&lA2[o] = p2;
      }
      int ob = bsr * LDP + bsc;
      *(h8*)&lB1[ob] = rb1a;
      *(h8*)&lB2[ob] = rb2a;
      if constexpr (BN == 128) {
        *(h8*)&lB1[ob + 8] = rb1b;
        *(h8*)&lB2[ob + 8] = rb2b;
      }
    }
    __syncthreads();
    if (kt < KSTEPS - 1) {  // prefetch next K-tile
      int kb = (kt + 1) * 32;
      if constexpr (FP16A) {
        const _Float16 *s1, *s2;
        int kk;
        if constexpr (DUAL) {
          s1 = (kb < DD) ? A1a : A1b;
          s2 = (kb < DD) ? A2a : A2b;
          kk = kb & (DD - 1);
        } else {
          s1 = A1a; s2 = A2a; kk = kb;
        }
        ra1 = *(const h8*)(s1 + (size_t)ga * ASTR + kk + asc);
        ra2 = *(const h8*)(s2 + (size_t)ga * ASTR + kk + asc);
      } else {
        const float* pa = Af + (size_t)ga * ASTR + kb + asc;
        fa0 = *(const float4*)(pa);
        fa1 = *(const float4*)(pa + 4);
      }
      rb1a = *(const h8*)(B1 + boff + kb);
      rb2a = *(const h8*)(B2 + boff + kb);
      if constexpr (BN == 128) {
        rb1b = *(const h8*)(B1 + boff + kb + 8);
        rb2b = *(const h8*)(B2 + boff + kb + 8);
      }
    }
    h8 a1[2], a2[2];
#pragma unroll
    for (int mi = 0; mi < 2; ++mi) {
      int r = (wr * 32 + mi * 16 + fr) * LDP + fs;
      a1[mi] = *(const h8*)&lA1[r];
      a2[mi] = *(const h8*)&lA2[r];
    }
#pragma unroll
    for (int ni = 0; ni < NFN; ++ni) {
      int c = (wc * (NFN * 16) + ni * 16 + fr) * LDP + fs;
      h8 b1 = *(const h8*)&lB1[c];
      h8 b2 = *(const h8*)&lB2[c];
#pragma unroll
      for (int mi = 0; mi < 2; ++mi) {
        acc[mi][ni] = __builtin_amdgcn_mfma_f32_16x16x32_f16(a1[mi], b1, acc[mi][ni], 0, 0, 0);
        acc[mi][ni] = __builtin_amdgcn_mfma_f32_16x16x32_f16(a1[mi], b2, acc[mi][ni], 0, 0, 0);
        acc[mi][ni] = __builtin_amdgcn_mfma_f32_16x16x32_f16(a2[mi], b1, acc[mi][ni], 0, 0, 0);
      }
    }
  }
  // epilogue: C/D layout col=lane&15, row=(lane>>4)*4+r (m89-verified)
#pragma unroll
  for (int ni = 0; ni < NFN; ++ni) {
    int col = j0 + wc * (NFN * 16) + ni * 16 + fr;
    float bv = bias[col];
#pragma unroll
    for (int mi = 0; mi < 2; ++mi) {
      int rbase = i0 + wr * 32 + mi * 16 + (lane >> 4) * 4;
#pragma unroll
      for (int r = 0; r < 4; ++r) {
        int row = rbase + r;
        if (row < NN) {
          float v = acc[mi][ni][r] + bv;
          outp[(size_t)row * OSTR + col] = RELU ? fmaxf(v, 0.f) : v;
        }
      }
    }
  }
}

extern "C" void kernel_launch(void* const* d_in, const int* in_sizes, int n_in,
                              void* d_out, int out_size, void* d_ws, size_t ws_size,
                              hipStream_t stream) {
  const float* x = (const float*)d_in[0];
  const int* ei = (const int*)d_in[1];
  const float* gn = (const float*)d_in[2];
  const float* W_enc = (const float*)d_in[3];
  const float* b_enc = (const float*)d_in[4];
  const float* W_root = (const float*)d_in[5];
  const float* W_agg = (const float*)d_in[6];
  const float* b_env = (const float*)d_in[7];
  const float* Wa_in_r = (const float*)d_in[8];
  const float* Wa_in_a = (const float*)d_in[9];
  const float* b_in = (const float*)d_in[10];
  const float* Wa_out_r = (const float*)d_in[11];
  const float* Wa_out_a = (const float*)d_in[12];
  const float* b_out = (const float*)d_in[13];
  // d_in[14..16] (Wt_r, Wt_a, b_t) are dead: hard gumbel = one_hot(argmax(logits+g)),
  // temp>0 never changes the argmax.
  const float* ln_g = (const float*)d_in[17];
  const float* ln_b = (const float*)d_in[18];
  const float* W_dec = (const float*)d_in[19];
  const float* b_dec = (const float*)d_in[20];
  float* out = (float*)d_out;

  float* ws = (float*)d_ws;
  size_t off = 0;
  float* h = ws + off;    off += (size_t)NN * DD;
  _Float16* hn1 = (_Float16*)(ws + off);  off += (size_t)NN * DD / 2;
  _Float16* hn2 = (_Float16*)(ws + off);  off += (size_t)NN * DD / 2;
  _Float16* agg1 = (_Float16*)(ws + off); off += (size_t)NN * DD / 2;
  _Float16* agg2 = (_Float16*)(ws + off); off += (size_t)NN * DD / 2;
  float* SR = ws + off;   off += (size_t)NN * 4;
  float* SA = ws + off;   off += (size_t)NN * 4;
  int* rowptr = (int*)(ws + off); off += (size_t)NN + 4;
  int* csr_v = (int*)(ws + off);  off += (size_t)EE;
  unsigned char* gin = (unsigned char*)(ws + off);  off += (size_t)NN / 4;
  unsigned char* gout = (unsigned char*)(ws + off); off += (size_t)NN / 4;
  _Float16* cW1 = (_Float16*)(ws + off); off += (size_t)NLAYERS * DD * DD;      // [3][256][512] halves
  _Float16* cW2 = (_Float16*)(ws + off); off += (size_t)NLAYERS * DD * DD;
  _Float16* eW1 = (_Float16*)(ws + off); off += (size_t)DD * DIN / 2;           // [256][128]
  _Float16* eW2 = (_Float16*)(ws + off); off += (size_t)DD * DIN / 2;
  _Float16* dW1 = (_Float16*)(ws + off); off += (size_t)DOUT * DD / 2;          // [64][256]
  _Float16* dW2 = (_Float16*)(ws + off); off += (size_t)DOUT * DD / 2;
  if (ws_size < off * sizeof(float)) return;  // insufficient scratch -> visible failure
  // CSR-build aliases (SR/SA rewritten by ln_scalars after build completes)
  int* deg = (int*)SR;
  int* bsum = (int*)SR + NN;
  int* boffp = (int*)SR + NN + 256;
  int* cursor = (int*)SA;

  k_zero_deg<<<(NN + 255) / 256, 256, 0, stream>>>(deg);
  k_deg<<<(EE + 255) / 256, 256, 0, stream>>>(ei, deg);
  k_scan1<<<NB_SCAN, 256, 0, stream>>>(deg, bsum);
  k_scan2<<<1, 256, 0, stream>>>(bsum, boffp, rowptr);
  k_scan3<<<NB_SCAN, 256, 0, stream>>>(deg, boffp, rowptr, cursor);
  k_fill<<<(EE + 255) / 256, 256, 0, stream>>>(ei, cursor, csr_v);

  k_prep_conv<<<(NLAYERS * DD * 2 * DD + 255) / 256, 256, 0, stream>>>(W_root, W_agg, cW1, cW2);
  k_prep_ed<<<(DIN * DD + DD * DOUT + 255) / 256, 256, 0, stream>>>(W_enc, W_dec,
                                                                    eW1, eW2, dW1, dW2);

  const int gy = (NN + BM - 1) / BM;
  // encoder: h = relu(x @ W_enc + b_enc)  (fp32 A, split in staging)
  k_mfma_gemm<DIN, DIN, 4, DD, true, false, false><<<dim3(2, gy), 256, 0, stream>>>(
      x, nullptr, nullptr, nullptr, nullptr, eW1, eW2, b_enc, h);

  for (int l = 0; l < NLAYERS; ++l) {
    k_ln_scalars<<<(NN + 3) / 4, 256, 0, stream>>>(h, ln_g, ln_b, Wa_in_r, Wa_in_a,
                                                   Wa_out_r, Wa_out_a, hn1, hn2, SR, SA);
    k_gates_csr<<<(NN + 255) / 256, 256, 0, stream>>>(rowptr, csr_v, SR, SA, gn,
                                                      b_in, b_out, gin, gout, l);
    k_wagg_csr<<<(NN + 3) / 4, 256, 0, stream>>>(rowptr, csr_v, gin, gout,
                                                 hn1, hn2, agg1, agg2);
    // conv: h = relu([hn|agg] @ [Wr;Wa] + b_env)  (pre-limbed fp16 A)
    k_mfma_gemm<2 * DD, DD, 4, DD, true, true, true><<<dim3(2, gy), 256, 0, stream>>>(
        nullptr, hn1, hn2, agg1, agg2,
        cW1 + (size_t)l * DD * 2 * DD, cW2 + (size_t)l * DD * 2 * DD,
        b_env + (size_t)l * DD, h);
  }

  k_ln_scalars<<<(NN + 3) / 4, 256, 0, stream>>>(h, ln_g, ln_b, Wa_in_r, Wa_in_a,
                                                 Wa_out_r, Wa_out_a, hn1, hn2, SR, SA);
  // decoder: out = hn @ W_dec + b_dec  (pre-limbed fp16 A)
  k_mfma_gemm<DD, DD, 2, DOUT, false, true, false><<<dim3(1, gy), 256, 0, stream>>>(
      nullptr, hn1, hn2, nullptr, nullptr, dW1, dW2, b_dec, out);
}